// Round 12
// baseline (621.345 us; speedup 1.0000x reference)
//
#include <hip/hip_runtime.h>

#define DEVI __device__ __forceinline__

typedef __attribute__((ext_vector_type(4))) float f32x4;
typedef __attribute__((ext_vector_type(8))) short s16x8;
typedef __attribute__((ext_vector_type(4))) short s16x4;
typedef __attribute__((ext_vector_type(2))) unsigned int u32x2;
typedef unsigned short u16;
typedef unsigned int u32;

// B=64, N=256, F=16, H=256, BN=16384, N_ITERS=10
#define WST 288   /* padded k-stride for Wz/Wr/Wh transposed (272 -> 288) */
#define AST 260   /* act LDS row stride: 520 B rows, b64-pair reads, 0 conflicts (R10) */

// s_waitcnt vmcnt(n) only (gfx9 encoding: expcnt/lgkmcnt = no-wait)
#define WAITVM(n) __builtin_amdgcn_s_waitcnt(((n)&0xF) | 0x70 | 0xF00 | (((n)>>4)<<14))

DEVI u16 f2bf(float x){
  u32 u = __float_as_uint(x);
  u = (u + 0x7fffu + ((u >> 16) & 1u)) >> 16;
  return (u16)u;
}
DEVI float bf2f(u16 v){ return __uint_as_float(((u32)v) << 16); }

DEVI float fsigm(float x){ return __builtin_amdgcn_rcpf(1.f + __builtin_amdgcn_exp2f(-1.442695041f * x)); }
DEVI float ftanh(float x){ float e = __builtin_amdgcn_exp2f(2.885390082f * x); return 1.f - 2.f * __builtin_amdgcn_rcpf(e + 1.f); }

DEVI s16x8 ld8(const u16* p){ return *(const s16x8*)p; }          // 16-B aligned
DEVI s16x8 ldb64p(const u16* p){                                   // 8-B aligned (two b64)
  s16x4 lo = *(const s16x4*)p;
  s16x4 hi = *(const s16x4*)(p + 4);
  s16x8 r;
  r[0]=lo[0]; r[1]=lo[1]; r[2]=lo[2]; r[3]=lo[3];
  r[4]=hi[0]; r[5]=hi[1]; r[6]=hi[2]; r[7]=hi[3];
  return r;
}

// ---- R11: non-temporal accessors for block-private streams (no L2 allocate;
// keeps the 32x-reused weights resident in the 4MB per-XCD L2). Semantics
// identical, caching only. NOTE: nontemporal builtins need clang vector
// types, not HIP_vector_type (uint2) — hence u32x2.
DEVI s16x8 ld8nt(const u16* p){ return __builtin_nontemporal_load((const s16x8*)p); }
DEVI f32x4 ld4bfnt(const u16* p){
  u32x2 v = __builtin_nontemporal_load((const u32x2*)p);
  f32x4 r;
  r[0] = bf2f((u16)(v[0] & 0xffff)); r[1] = bf2f((u16)(v[0] >> 16));
  r[2] = bf2f((u16)(v[1] & 0xffff)); r[3] = bf2f((u16)(v[1] >> 16));
  return r;
}

DEVI f32x4 ld4bf(const u16* p){
  uint2 v = *(const uint2*)p;
  f32x4 r;
  r[0] = bf2f((u16)(v.x & 0xffff)); r[1] = bf2f((u16)(v.x >> 16));
  r[2] = bf2f((u16)(v.y & 0xffff)); r[3] = bf2f((u16)(v.y >> 16));
  return r;
}

DEVI void st4bf(u16* p, float a, float b, float c, float d){
  uint2 v;
  v.x = (u32)f2bf(a) | ((u32)f2bf(b) << 16);
  v.y = (u32)f2bf(c) | ((u32)f2bf(d) << 16);
  *(uint2*)p = v;
}
DEVI void st4bfnt(u16* p, float a, float b, float c, float d){
  u32x2 v;
  v[0] = (u32)f2bf(a) | ((u32)f2bf(b) << 16);
  v[1] = (u32)f2bf(c) | ((u32)f2bf(d) << 16);
  __builtin_nontemporal_store(v, (u32x2*)p);
}

#define MFMA(a,b,c) __builtin_amdgcn_mfma_f32_16x16x32_bf16((a),(b),(c),0,0,0)

// Stage one [64 rows][32 k] tile chunk into wave-private LDS via async DMA
// (4 x 1KB instrs). Source col XOR-swizzled (col ^= (row>>1)&3) so AFRAG's
// ds_read_b128 lands 2-way per bank (R10-measured: 0 conflicts).
DEVI void dma4(const u16* lanebase, int rowStrideElems, int c, u16* ldsbase){
#pragma unroll
  for(int q = 0; q < 4; q++){
    const u16* g = lanebase + (size_t)q*16*rowStrideElems + c*32;
    __builtin_amdgcn_global_load_lds((__attribute__((address_space(1))) const void*)g,
                                     (__attribute__((address_space(3))) void*)(ldsbase + q*512),
                                     16, 0, 0);
  }
}
// A-fragment read: subtile t (16 rows), row ln, k-quad qd (swizzle-matched)
#define AFRAG(buf, t) ld8(&(buf)[(t)*512 + ln*32 + ((qd ^ ((ln>>1)&3))*8)])

// ---------------------------------------------------------------------------
// Prep (coalesced-read transposes) — unchanged
// ---------------------------------------------------------------------------
__global__ void k_prep(
  const float* __restrict__ jets, const float* __restrict__ dads, const float* __restrict__ W_emb,
  const float* __restrict__ W_msg, const float* __restrict__ Wz, const float* __restrict__ Uz,
  const float* __restrict__ Wr, const float* __restrict__ Ur, const float* __restrict__ Wh,
  const float* __restrict__ Uh, const float* __restrict__ W_r1,
  u16* __restrict__ jp, u16* __restrict__ dadsb, u16* __restrict__ Wet, u16* __restrict__ Wmt,
  u16* __restrict__ Wzt, u16* __restrict__ Uzt, u16* __restrict__ Wrt, u16* __restrict__ Urt,
  u16* __restrict__ Wht, u16* __restrict__ Uht, u16* __restrict__ Wr1t)
{
  int blk = blockIdx.x, tid = threadIdx.x;
  if(blk < 1280){
    int mi = blk >> 8, k = blk & 255, j = tid;
    const float* src; u16* dst;
    switch(mi){
      case 0: src = W_msg; dst = Wmt;  break;
      case 1: src = Uz;    dst = Uzt;  break;
      case 2: src = Ur;    dst = Urt;  break;
      case 3: src = Uh;    dst = Uht;  break;
      default: src = W_r1; dst = Wr1t; break;
    }
    dst[j*256 + k] = f2bf(src[k*256 + j]);
  } else if(blk < 2144){
    int q = blk - 1280; int mi = q / 288; int k = q - mi*288; int j = tid;
    const float* src; u16* dst;
    switch(mi){ case 0: src = Wz; dst = Wzt; break; case 1: src = Wr; dst = Wrt; break; default: src = Wh; dst = Wht; break; }
    dst[j*WST + k] = (k < 272) ? f2bf(src[k*256 + j]) : (u16)0;
  } else if(blk < 2176){
    int idx = (blk - 2144)*256 + tid;
    int j = idx >> 5, k = idx & 31;
    Wet[idx] = (k < 16) ? f2bf(W_emb[k*256 + j]) : (u16)0;
  } else if(blk < 4224){
    int idx = (blk - 2176)*256 + tid;
    int n = idx >> 5, k = idx & 31;
    jp[idx] = (k < 16) ? f2bf(jets[n*16 + k]) : (u16)0;
  } else {
    int idx = (blk - 4224)*256 + tid;
    f32x4 v = *(const f32x4*)(dads + (size_t)idx*4);
    st4bf(dadsb + (size_t)idx*4, v[0], v[1], v[2], v[3]);
  }
}

// ---------------------------------------------------------------------------
// k_embed2 (R9 + R10 rotation): 256 blocks x 64 nodes.
// ---------------------------------------------------------------------------
__global__ void k_embed2(
  u16* __restrict__ h, u16* __restrict__ hmo,
  const u16* __restrict__ jp, const u16* __restrict__ Wet, const float* __restrict__ be,
  const u16* __restrict__ Wmt, const float* __restrict__ bm)
{
  __shared__ u16 smM[64*AST];
  const int tid = threadIdx.x;
  const int wv = tid >> 6, lane = tid & 63, ln = lane & 15, qd = lane >> 4;
  const int blk   = blockIdx.x;
  const int batch = (blk & 7) * 8 + (blk >> 5);
  const int group = (blk >> 3) & 3;
  const int n0 = batch * 256 + group * 64;
  const int b  = batch;
  const int nb = group * 64;
  const int j0w = wv * 64;
  const int c0 = (blk >> 3) & 7;

  s16x8 jB[4];
#pragma unroll
  for(int i = 0; i < 4; i++) jB[i] = ld8(jp + (size_t)(n0 + i*16 + ln)*32 + qd*8);

  // ---- Phase E: embed ----
#pragma unroll
  for(int t = 0; t < 4; t++){
    s16x8 a = ld8(Wet + (size_t)(j0w + t*16 + ln)*32 + qd*8);
    f32x4 bv = *(const f32x4*)(be + j0w + t*16 + qd*4);
#pragma unroll
    for(int i = 0; i < 4; i++){
      f32x4 acc = {0.f,0.f,0.f,0.f};
      acc = MFMA(a, jB[i], acc);
      f32x4 hv;
#pragma unroll
      for(int r = 0; r < 4; r++) hv[r] = ftanh(acc[r] + bv[r]);
      st4bf(h + (size_t)(n0 + i*16 + ln)*256 + j0w + t*16 + qd*4, hv[0], hv[1], hv[2], hv[3]);
      st4bf(&smM[(i*16 + ln)*AST + j0w + t*16 + qd*4], hv[0], hv[1], hv[2], hv[3]);
    }
  }
  __syncthreads();

  // ---- Phase M: hm = h @ W_msg + b_msg -> [b][j][node] ----
  {
    f32x4 acc[4][4];
#pragma unroll
    for(int t = 0; t < 4; t++)
#pragma unroll
      for(int i = 0; i < 4; i++) acc[t][i] = (f32x4){0.f,0.f,0.f,0.f};
#pragma unroll
    for(int c = 0; c < 8; c++){
      const int cc = (c + c0) & 7;
      s16x8 A[4];
#pragma unroll
      for(int t = 0; t < 4; t++) A[t] = ld8(Wmt + (size_t)(j0w + t*16 + ln)*256 + cc*32 + qd*8);
      s16x8 Bf[4];
#pragma unroll
      for(int i = 0; i < 4; i++) Bf[i] = ldb64p(&smM[(i*16 + ln)*AST + cc*32 + qd*8]);
#pragma unroll
      for(int t = 0; t < 4; t++)
#pragma unroll
        for(int i = 0; i < 4; i++) acc[t][i] = MFMA(A[t], Bf[i], acc[t][i]);
    }
#pragma unroll
    for(int t = 0; t < 4; t++){
      f32x4 bmv = *(const f32x4*)(bm + j0w + t*16 + qd*4);
#pragma unroll
      for(int i = 0; i < 4; i++){
#pragma unroll
        for(int r = 0; r < 4; r++){
          hmo[(size_t)(b*256 + j0w + t*16 + qd*4 + r)*256 + nb + i*16 + ln] =
            f2bf(acc[t][i][r] + bmv[r]);
        }
      }
    }
  }
}

// ---------------------------------------------------------------------------
// k_gru v23 = v22 (R10 rotation) + R11 cache-policy segregation: per-XCD
// working set was 4.1MB > 4MB L2 (8 batches x {hm,dads,h} + 1.07MB weights);
// block-private streams (dads rows, h rows — zero cross-block reuse, reuse
// distance one launch) evicted the 32x-reused weights, forcing weight reads
// to L3 (~800cyc) -> the measured 28.6 GB/s/CU cap. NT loads/stores on the
// private streams keep weights + hm L2-resident (~3.1MB < 4MB).
// ---------------------------------------------------------------------------
__global__ __launch_bounds__(256,1) void k_gru(
  u16* __restrict__ h,
  const u16* __restrict__ hmi, u16* __restrict__ hmo,
  const u16* __restrict__ dadsb, const u16* __restrict__ jp,
  const u16* __restrict__ Wzt, const u16* __restrict__ Wrt, const u16* __restrict__ Wht,
  const u16* __restrict__ Uzt, const u16* __restrict__ Urt, const u16* __restrict__ Uht,
  const u16* __restrict__ Wmt,
  const float* __restrict__ bz, const float* __restrict__ br, const float* __restrict__ bhb,
  const float* __restrict__ bm)
{
  __shared__ u16 smM[64*AST];                       // m, later h_new
  __shared__ u16 smB[64*AST];                       // rh
  __shared__ __align__(16) u16 stg[4][2][2][2048];  // [wave][buf][mat] 64 KB
  const int tid = threadIdx.x;
  const int wv = tid >> 6, lane = tid & 63, ln = lane & 15, qd = lane >> 4;
  const int blk   = blockIdx.x;
  const int batch = (blk & 7) * 8 + (blk >> 5);
  const int group = (blk >> 3) & 3;
  const int n0 = batch * 256 + group * 64;
  const int b  = batch;
  const int nb = group * 64;
  const int j0w = wv * 64;                 // wave's 64-wide j-quarter
  const int c0 = (blk >> 3) & 7;           // R10 rotation offset
#define CHK(x) (((x) + c0) & 7)

  u16* s0 = &stg[wv][0][0][0];
  u16* s1 = &stg[wv][1][0][0];
  u16* u0 = &stg[wv][0][1][0];
  u16* u1 = &stg[wv][1][1][0];

  // per-lane DMA source addressing (row = lane>>2, XOR-swizzled col)
  const int rw = lane >> 2;
  const int cs = ((lane & 3) ^ ((lane >> 3) & 3)) * 8;

  // stage1 chunk-0 prefetch ASAP
  const u16* laneA = hmi + (size_t)(b*256 + j0w + rw)*256 + cs;
  dma4(laneA, 256, CHK(0), s0);

  s16x8 jB[4];
#pragma unroll
  for(int i = 0; i < 4; i++) jB[i] = ld8(jp + (size_t)(n0 + i*16 + ln)*32 + qd*8);

  // ================= stage1: m = tanh(dads @ hm) =================
  {
    f32x4 acc[4][4];
#pragma unroll
    for(int t = 0; t < 4; t++)
#pragma unroll
      for(int i = 0; i < 4; i++) acc[t][i] = (f32x4){0.f,0.f,0.f,0.f};
    s16x8 Bf[4], Bn[4];
#pragma unroll
    for(int i = 0; i < 4; i++) Bf[i] = ld8nt(dadsb + (size_t)(n0 + i*16 + ln)*256 + CHK(0)*32 + qd*8);
#pragma unroll
    for(int c = 0; c < 8; c++){
      u16* cur = (c & 1) ? s1 : s0;
      if(c < 7){
        dma4(laneA, 256, CHK(c+1), (c & 1) ? s0 : s1);
#pragma unroll
        for(int i = 0; i < 4; i++) Bn[i] = ld8nt(dadsb + (size_t)(n0 + i*16 + ln)*256 + CHK(c+1)*32 + qd*8);
        WAITVM(8);
      } else {
        WAITVM(0);
      }
#pragma unroll
      for(int t = 0; t < 4; t++){
        s16x8 A = AFRAG(cur, t);
#pragma unroll
        for(int i = 0; i < 4; i++) acc[t][i] = MFMA(A, Bf[i], acc[t][i]);
      }
      if(c < 7){
#pragma unroll
        for(int i = 0; i < 4; i++) Bf[i] = Bn[i];
      }
    }
#pragma unroll
    for(int t = 0; t < 4; t++)
#pragma unroll
      for(int i = 0; i < 4; i++)
        st4bf(&smM[(i*16 + ln)*AST + j0w + t*16 + qd*4],
              ftanh(acc[t][i][0]), ftanh(acc[t][i][1]), ftanh(acc[t][i][2]), ftanh(acc[t][i][3]));
  }
  // r-phase chunk-0 prefetch before the barrier (wave-private buffers)
  const u16* laneWr = Wrt + (size_t)(j0w + rw)*WST + cs;
  const u16* laneUr = Urt + (size_t)(j0w + rw)*256 + cs;
  dma4(laneWr, WST, CHK(0), s0);
  dma4(laneUr, 256, CHK(0), u0);
  __syncthreads();

  // ================= r-pass: rh = sig(m@Wr + jets@Wr' + h@Ur + br)*h =================
  {
    f32x4 acc[4][4];
#pragma unroll
    for(int t = 0; t < 4; t++)
#pragma unroll
      for(int i = 0; i < 4; i++) acc[t][i] = (f32x4){0.f,0.f,0.f,0.f};
    s16x8 Aj[4];
#pragma unroll
    for(int t = 0; t < 4; t++) Aj[t] = ld8(Wrt + (size_t)(j0w + t*16 + ln)*WST + 256 + qd*8);
    s16x8 Bh[4], Bn[4];
#pragma unroll
    for(int i = 0; i < 4; i++) Bh[i] = ld8nt(h + (size_t)(n0 + i*16 + ln)*256 + CHK(0)*32 + qd*8);
#pragma unroll
    for(int c = 0; c < 8; c++){
      u16* cw = (c & 1) ? s1 : s0;
      u16* cu = (c & 1) ? u1 : u0;
      if(c < 7){
        dma4(laneWr, WST, CHK(c+1), (c & 1) ? s0 : s1);
        dma4(laneUr, 256, CHK(c+1), (c & 1) ? u0 : u1);
#pragma unroll
        for(int i = 0; i < 4; i++) Bn[i] = ld8nt(h + (size_t)(n0 + i*16 + ln)*256 + CHK(c+1)*32 + qd*8);
        WAITVM(12);
      } else {
        WAITVM(0);
      }
      s16x8 Bm[4];
#pragma unroll
      for(int i = 0; i < 4; i++) Bm[i] = ldb64p(&smM[(i*16 + ln)*AST + CHK(c)*32 + qd*8]);
#pragma unroll
      for(int t = 0; t < 4; t++){
        s16x8 Aw = AFRAG(cw, t);
#pragma unroll
        for(int i = 0; i < 4; i++) acc[t][i] = MFMA(Aw, Bm[i], acc[t][i]);
      }
#pragma unroll
      for(int t = 0; t < 4; t++){
        s16x8 Au = AFRAG(cu, t);
#pragma unroll
        for(int i = 0; i < 4; i++) acc[t][i] = MFMA(Au, Bh[i], acc[t][i]);
      }
      if(c < 7){
#pragma unroll
        for(int i = 0; i < 4; i++) Bh[i] = Bn[i];
      }
    }
#pragma unroll
    for(int t = 0; t < 4; t++)
#pragma unroll
      for(int i = 0; i < 4; i++) acc[t][i] = MFMA(Aj[t], jB[i], acc[t][i]);
#pragma unroll
    for(int t = 0; t < 4; t++){
      f32x4 bv = *(const f32x4*)(br + j0w + t*16 + qd*4);
#pragma unroll
      for(int i = 0; i < 4; i++){
        f32x4 hv = ld4bfnt(h + (size_t)(n0 + i*16 + ln)*256 + j0w + t*16 + qd*4);
        st4bf(&smB[(i*16 + ln)*AST + j0w + t*16 + qd*4],
              fsigm(acc[t][i][0]+bv[0])*hv[0], fsigm(acc[t][i][1]+bv[1])*hv[1],
              fsigm(acc[t][i][2]+bv[2])*hv[2], fsigm(acc[t][i][3]+bv[3])*hv[3]);
      }
    }
  }
  // z-phase chunk-0 prefetch (after epilogue so its hv-load waits don't drain us)
  const u16* laneWz = Wzt + (size_t)(j0w + rw)*WST + cs;
  const u16* laneUz = Uzt + (size_t)(j0w + rw)*256 + cs;
  dma4(laneWz, WST, CHK(0), s0);
  dma4(laneUz, 256, CHK(0), u0);
  __syncthreads();

  // ================= z-phase: zacc = m@Wz + jets@Wz' + h@Uz =================
  f32x4 zacc[4][4], gacc[4][4];
#pragma unroll
  for(int t = 0; t < 4; t++)
#pragma unroll
    for(int i = 0; i < 4; i++) zacc[t][i] = (f32x4){0.f,0.f,0.f,0.f};
  {
    s16x8 Aj[4];
#pragma unroll
    for(int t = 0; t < 4; t++) Aj[t] = ld8(Wzt + (size_t)(j0w + t*16 + ln)*WST + 256 + qd*8);
    s16x8 Bh[4], Bn[4];
#pragma unroll
    for(int i = 0; i < 4; i++) Bh[i] = ld8nt(h + (size_t)(n0 + i*16 + ln)*256 + CHK(0)*32 + qd*8);
#pragma unroll
    for(int c = 0; c < 8; c++){
      u16* cw = (c & 1) ? s1 : s0;
      u16* cu = (c & 1) ? u1 : u0;
      if(c < 7){
        dma4(laneWz, WST, CHK(c+1), (c & 1) ? s0 : s1);
        dma4(laneUz, 256, CHK(c+1), (c & 1) ? u0 : u1);
#pragma unroll
        for(int i = 0; i < 4; i++) Bn[i] = ld8nt(h + (size_t)(n0 + i*16 + ln)*256 + CHK(c+1)*32 + qd*8);
        WAITVM(12);
      } else {
        WAITVM(0);
      }
      s16x8 Bm[4];
#pragma unroll
      for(int i = 0; i < 4; i++) Bm[i] = ldb64p(&smM[(i*16 + ln)*AST + CHK(c)*32 + qd*8]);
#pragma unroll
      for(int t = 0; t < 4; t++){
        s16x8 Aw = AFRAG(cw, t);
#pragma unroll
        for(int i = 0; i < 4; i++) zacc[t][i] = MFMA(Aw, Bm[i], zacc[t][i]);
      }
#pragma unroll
      for(int t = 0; t < 4; t++){
        s16x8 Au = AFRAG(cu, t);
#pragma unroll
        for(int i = 0; i < 4; i++) zacc[t][i] = MFMA(Au, Bh[i], zacc[t][i]);
      }
      if(c < 7){
#pragma unroll
        for(int i = 0; i < 4; i++) Bh[i] = Bn[i];
      }
    }
#pragma unroll
    for(int t = 0; t < 4; t++)
#pragma unroll
      for(int i = 0; i < 4; i++) zacc[t][i] = MFMA(Aj[t], jB[i], zacc[t][i]);
  }

  // g-phase chunk-0 prefetch (no barrier needed; z's last chunk read buf1)
  const u16* laneWh = Wht + (size_t)(j0w + rw)*WST + cs;
  const u16* laneUh = Uht + (size_t)(j0w + rw)*256 + cs;
  dma4(laneWh, WST, CHK(0), s0);
  dma4(laneUh, 256, CHK(0), u0);

  // ================= g-phase: gacc = m@Wh + jets@Wh' + rh@Uh =================
#pragma unroll
  for(int t = 0; t < 4; t++)
#pragma unroll
    for(int i = 0; i < 4; i++) gacc[t][i] = (f32x4){0.f,0.f,0.f,0.f};
  {
    s16x8 Aj[4];
#pragma unroll
    for(int t = 0; t < 4; t++) Aj[t] = ld8(Wht + (size_t)(j0w + t*16 + ln)*WST + 256 + qd*8);
#pragma unroll
    for(int c = 0; c < 8; c++){
      u16* cw = (c & 1) ? s1 : s0;
      u16* cu = (c & 1) ? u1 : u0;
      if(c < 7){
        dma4(laneWh, WST, CHK(c+1), (c & 1) ? s0 : s1);
        dma4(laneUh, 256, CHK(c+1), (c & 1) ? u0 : u1);
        WAITVM(8);
      } else {
        WAITVM(0);
      }
      s16x8 Bm[4], Brh[4];
#pragma unroll
      for(int i = 0; i < 4; i++){
        Bm[i]  = ldb64p(&smM[(i*16 + ln)*AST + CHK(c)*32 + qd*8]);
        Brh[i] = ldb64p(&smB[(i*16 + ln)*AST + CHK(c)*32 + qd*8]);
      }
#pragma unroll
      for(int t = 0; t < 4; t++){
        s16x8 Aw = AFRAG(cw, t);
#pragma unroll
        for(int i = 0; i < 4; i++) gacc[t][i] = MFMA(Aw, Bm[i], gacc[t][i]);
      }
#pragma unroll
      for(int t = 0; t < 4; t++){
        s16x8 Au = AFRAG(cu, t);
#pragma unroll
        for(int i = 0; i < 4; i++) gacc[t][i] = MFMA(Au, Brh[i], gacc[t][i]);
      }
    }
#pragma unroll
    for(int t = 0; t < 4; t++)
#pragma unroll
      for(int i = 0; i < 4; i++) gacc[t][i] = MFMA(Aj[t], jB[i], gacc[t][i]);
  }
  __syncthreads();   // all smM/smB reads complete before epilogue overwrites smM

  // ================= epilogue: h_new = h + z*(tanh(g)-h) =================
#pragma unroll
  for(int t = 0; t < 4; t++){
    f32x4 bzv = *(const f32x4*)(bz + j0w + t*16 + qd*4);
    f32x4 bhv = *(const f32x4*)(bhb + j0w + t*16 + qd*4);
#pragma unroll
    for(int i = 0; i < 4; i++){
      f32x4 hv = ld4bfnt(h + (size_t)(n0 + i*16 + ln)*256 + j0w + t*16 + qd*4);
      f32x4 hn;
#pragma unroll
      for(int r = 0; r < 4; r++){
        float z  = fsigm(zacc[t][i][r] + bzv[r]);
        float th = ftanh(gacc[t][i][r] + bhv[r]);
        hn[r] = hv[r] + z * (th - hv[r]);
      }
      st4bfnt(h + (size_t)(n0 + i*16 + ln)*256 + j0w + t*16 + qd*4, hn[0], hn[1], hn[2], hn[3]);
      st4bf(&smM[(i*16 + ln)*AST + j0w + t*16 + qd*4], hn[0], hn[1], hn[2], hn[3]);
    }
  }
  // msg chunk-0 prefetch (after epilogue, before barrier)
  const u16* laneWm = Wmt + (size_t)(j0w + rw)*256 + cs;
  dma4(laneWm, 256, CHK(0), s0);
  __syncthreads();

  // ================= msg: hm_out = h_new @ W_msg + b_msg -> [b][h][node] =================
  {
    f32x4 acc[4][4];
#pragma unroll
    for(int t = 0; t < 4; t++)
#pragma unroll
      for(int i = 0; i < 4; i++) acc[t][i] = (f32x4){0.f,0.f,0.f,0.f};
#pragma unroll
    for(int c = 0; c < 8; c++){
      u16* cur = (c & 1) ? s1 : s0;
      if(c < 7){
        dma4(laneWm, 256, CHK(c+1), (c & 1) ? s0 : s1);
        WAITVM(4);
      } else {
        WAITVM(0);
      }
      s16x8 Bf[4];
#pragma unroll
      for(int i = 0; i < 4; i++) Bf[i] = ldb64p(&smM[(i*16 + ln)*AST + CHK(c)*32 + qd*8]);
#pragma unroll
      for(int t = 0; t < 4; t++){
        s16x8 A = AFRAG(cur, t);
#pragma unroll
        for(int i = 0; i < 4; i++) acc[t][i] = MFMA(A, Bf[i], acc[t][i]);
      }
    }
#pragma unroll
    for(int t = 0; t < 4; t++){
      f32x4 bmv = *(const f32x4*)(bm + j0w + t*16 + qd*4);
#pragma unroll
      for(int i = 0; i < 4; i++){
#pragma unroll
        for(int r = 0; r < 4; r++){
          __builtin_nontemporal_store(f2bf(acc[t][i][r] + bmv[r]),
            &hmo[(size_t)(b*256 + j0w + t*16 + qd*4 + r)*256 + nb + i*16 + ln]);
        }
      }
    }
  }
#undef CHK
}

// ---------------------------------------------------------------------------
// k_tred (R9 + R10 rotation + R11 NT h-reads): fused readout stage-1 + sum.
// ---------------------------------------------------------------------------
__global__ void k_tred(
  const u16* __restrict__ h, float* __restrict__ sred,
  const u16* __restrict__ Wr1t, const float* __restrict__ br1)
{
  const int tid = threadIdx.x;
  const int wv = tid >> 6, lane = tid & 63, ln = lane & 15, qd = lane >> 4;
  const int blk   = blockIdx.x;
  const int batch = (blk & 7) * 8 + (blk >> 5);
  const int group = (blk >> 3) & 3;
  const int n0 = batch * 256 + group * 64;
  const int j0w = wv * 64;
  const int c0 = (blk >> 3) & 7;

  f32x4 acc[4][4];
#pragma unroll
  for(int t = 0; t < 4; t++)
#pragma unroll
    for(int i = 0; i < 4; i++) acc[t][i] = (f32x4){0.f,0.f,0.f,0.f};
#pragma unroll
  for(int c = 0; c < 8; c++){
    const int cc = (c + c0) & 7;
    s16x8 A[4];
#pragma unroll
    for(int t = 0; t < 4; t++) A[t] = ld8(Wr1t + (size_t)(j0w + t*16 + ln)*256 + cc*32 + qd*8);
    s16x8 Bf[4];
#pragma unroll
    for(int i = 0; i < 4; i++) Bf[i] = ld8nt(h + (size_t)(n0 + i*16 + ln)*256 + cc*32 + qd*8);
#pragma unroll
    for(int t = 0; t < 4; t++)
#pragma unroll
      for(int i = 0; i < 4; i++) acc[t][i] = MFMA(A[t], Bf[i], acc[t][i]);
  }
#pragma unroll
  for(int t = 0; t < 4; t++){
    f32x4 bv = *(const f32x4*)(br1 + j0w + t*16 + qd*4);
    f32x4 s = {0.f,0.f,0.f,0.f};
#pragma unroll
    for(int i = 0; i < 4; i++)
#pragma unroll
      for(int r = 0; r < 4; r++) s[r] += ftanh(acc[t][i][r] + bv[r]);
    // cross-lane sum over ln (16 lanes share (qd,t,r) => same j)
#pragma unroll
    for(int r = 0; r < 4; r++){
      float v = s[r];
      v += __shfl_xor(v, 1);
      v += __shfl_xor(v, 2);
      v += __shfl_xor(v, 4);
      v += __shfl_xor(v, 8);
      s[r] = v;
    }
    if(ln == 0){
      *(f32x4*)&sred[(size_t)(batch*4 + group)*256 + j0w + t*16 + qd*4] = s;
    }
  }
}

// ---------------------------------------------------------------------------
// k_red2 (R9 + R10 k-rotation): out = 256*b_r2 + (sum_g sred) @ W_r2.
// ---------------------------------------------------------------------------
__global__ void k_red2(const float* __restrict__ sred, const float* __restrict__ W_r2,
                       const float* __restrict__ b_r2, float* __restrict__ out){
  __shared__ float red[4][64];
  const int blk = blockIdx.x;
  const int b = blk >> 2, jq = blk & 3;
  const int jl = threadIdx.x & 63, kq = threadIdx.x >> 6;
  const int j = jq*64 + jl;
  const float* s0 = sred + (size_t)b*4*256;
  float acc = 0.f;
  for(int kk = 0; kk < 64; kk++){
    int k = kq*64 + ((kk + b) & 63);   // rotate: 64 same-tile blocks de-correlate
    float s = s0[k] + s0[256 + k] + s0[512 + k] + s0[768 + k];
    acc += s * W_r2[(size_t)k*256 + j];
  }
  red[kq][jl] = acc;
  __syncthreads();
  if(kq == 0){
    out[(size_t)b*256 + j] = 256.f * b_r2[j] + red[0][jl] + red[1][jl] + red[2][jl] + red[3][jl];
  }
}

extern "C" void kernel_launch(void* const* d_in, const int* in_sizes, int n_in,
                              void* d_out, int out_size, void* d_ws, size_t ws_size,
                              hipStream_t stream)
{
  const float* jets  = (const float*)d_in[0];
  const float* dads  = (const float*)d_in[1];
  const float* W_emb = (const float*)d_in[2];
  const float* b_emb = (const float*)d_in[3];
  const float* W_msg = (const float*)d_in[4];
  const float* b_msg = (const float*)d_in[5];
  const float* Wz    = (const float*)d_in[6];
  const float* Uz    = (const float*)d_in[7];
  const float* bz    = (const float*)d_in[8];
  const float* Wr    = (const float*)d_in[9];
  const float* Ur    = (const float*)d_in[10];
  const float* br    = (const float*)d_in[11];
  const float* Wh    = (const float*)d_in[12];
  const float* Uh    = (const float*)d_in[13];
  const float* bh    = (const float*)d_in[14];
  const float* W_r1  = (const float*)d_in[15];
  const float* b_r1  = (const float*)d_in[16];
  const float* W_r2  = (const float*)d_in[17];
  const float* b_r2  = (const float*)d_in[18];

  char* ws = (char*)d_ws;
  u16* h      = (u16*)(ws);                    // 8 MB  [16384][256] bf16
  u16* hmA    = (u16*)(ws + 8388608);          // 8 MB  [64][256 h][256 node] bf16
  u16* hmB    = (u16*)(ws + 16777216);         // 8 MB  (free after gru: reused for sred)
  u16* dadsb  = (u16*)(ws + 25165824);         // 8 MB  [16384][256] bf16
  u16* jp     = (u16*)(ws + 33554432);         // 1 MB  [16384][32] bf16
  u16* Wmt    = (u16*)(ws + 34603008);
  u16* Uzt    = (u16*)(ws + 34734080);
  u16* Urt    = (u16*)(ws + 34865152);
  u16* Uht    = (u16*)(ws + 34996224);
  u16* Wr1t   = (u16*)(ws + 35127296);
  u16* Wzt    = (u16*)(ws + 35258368);
  u16* Wrt    = (u16*)(ws + 35405824);
  u16* Wht    = (u16*)(ws + 35553280);
  u16* Wet    = (u16*)(ws + 35700736);
  float* sred = (float*)(ws + 16777216);       // 256 KB f32 [64*4][256] (in hmB)
  float* outp = (float*)d_out;

  k_prep<<<8320, 256, 0, stream>>>(jets, dads, W_emb, W_msg, Wz, Uz, Wr, Ur, Wh, Uh, W_r1,
                                   jp, dadsb, Wet, Wmt, Wzt, Uzt, Wrt, Urt, Wht, Uht, Wr1t);
  k_embed2<<<256, 256, 0, stream>>>(h, hmA, jp, Wet, b_emb, Wmt, b_msg);
  for(int it = 0; it < 10; ++it){
    const u16* hin = (it & 1) ? hmB : hmA;
    u16* hout      = (it & 1) ? hmA : hmB;
    k_gru<<<256, 256, 0, stream>>>(h, hin, hout, dadsb, jp,
                                   Wzt, Wrt, Wht, Uzt, Urt, Uht, Wmt,
                                   bz, br, bh, b_msg);
  }
  // it=9 wrote hmA, so hmB region is free: sred lives there
  k_tred<<<256, 256, 0, stream>>>(h, sred, Wr1t, b_r1);
  k_red2<<<256, 256, 0, stream>>>(sred, W_r2, b_r2, outp);
}

// Round 13
// 521.647 us; speedup vs baseline: 1.1911x; 1.1911x over previous
//
#include <hip/hip_runtime.h>

#define DEVI __device__ __forceinline__

typedef __attribute__((ext_vector_type(4))) float f32x4;
typedef __attribute__((ext_vector_type(8))) short s16x8;
typedef __attribute__((ext_vector_type(4))) short s16x4;
typedef unsigned short u16;
typedef unsigned int u32;

// B=64, N=256, F=16, H=256, BN=16384, N_ITERS=10
#define WST 288   /* padded k-stride for Wz/Wr/Wh transposed (272 -> 288) */
#define AST 260   /* act LDS row stride: 520 B rows, b64-pair reads, 0 conflicts (R10) */

// s_waitcnt vmcnt(n) only (gfx9 encoding: expcnt/lgkmcnt = no-wait)
#define WAITVM(n) __builtin_amdgcn_s_waitcnt(((n)&0xF) | 0x70 | 0xF00 | (((n)>>4)<<14))

DEVI u16 f2bf(float x){
  u32 u = __float_as_uint(x);
  u = (u + 0x7fffu + ((u >> 16) & 1u)) >> 16;
  return (u16)u;
}
DEVI float bf2f(u16 v){ return __uint_as_float(((u32)v) << 16); }

DEVI float fsigm(float x){ return __builtin_amdgcn_rcpf(1.f + __builtin_amdgcn_exp2f(-1.442695041f * x)); }
DEVI float ftanh(float x){ float e = __builtin_amdgcn_exp2f(2.885390082f * x); return 1.f - 2.f * __builtin_amdgcn_rcpf(e + 1.f); }

DEVI s16x8 ld8(const u16* p){ return *(const s16x8*)p; }          // 16-B aligned
DEVI s16x8 ldb64p(const u16* p){                                   // 8-B aligned (two b64)
  s16x4 lo = *(const s16x4*)p;
  s16x4 hi = *(const s16x4*)(p + 4);
  s16x8 r;
  r[0]=lo[0]; r[1]=lo[1]; r[2]=lo[2]; r[3]=lo[3];
  r[4]=hi[0]; r[5]=hi[1]; r[6]=hi[2]; r[7]=hi[3];
  return r;
}

DEVI f32x4 ld4bf(const u16* p){
  uint2 v = *(const uint2*)p;
  f32x4 r;
  r[0] = bf2f((u16)(v.x & 0xffff)); r[1] = bf2f((u16)(v.x >> 16));
  r[2] = bf2f((u16)(v.y & 0xffff)); r[3] = bf2f((u16)(v.y >> 16));
  return r;
}

DEVI void st4bf(u16* p, float a, float b, float c, float d){
  uint2 v;
  v.x = (u32)f2bf(a) | ((u32)f2bf(b) << 16);
  v.y = (u32)f2bf(c) | ((u32)f2bf(d) << 16);
  *(uint2*)p = v;
}

#define MFMA(a,b,c) __builtin_amdgcn_mfma_f32_16x16x32_bf16((a),(b),(c),0,0,0)

// Stage one [64 rows][32 k] tile chunk into wave-private LDS via async DMA
// (4 x 1KB instrs). Source col XOR-swizzled (col ^= (row>>1)&3) so AFRAG's
// ds_read_b128 lands 2-way per bank (R10-measured: 0 conflicts).
DEVI void dma4(const u16* lanebase, int rowStrideElems, int c, u16* ldsbase){
#pragma unroll
  for(int q = 0; q < 4; q++){
    const u16* g = lanebase + (size_t)q*16*rowStrideElems + c*32;
    __builtin_amdgcn_global_load_lds((__attribute__((address_space(1))) const void*)g,
                                     (__attribute__((address_space(3))) void*)(ldsbase + q*512),
                                     16, 0, 0);
  }
}
// A-fragment read: subtile t (16 rows), row ln, k-quad qd (swizzle-matched)
#define AFRAG(buf, t) ld8(&(buf)[(t)*512 + ln*32 + ((qd ^ ((ln>>1)&3))*8)])

// ---------------------------------------------------------------------------
// Prep (coalesced-read transposes) — unchanged
// ---------------------------------------------------------------------------
__global__ void k_prep(
  const float* __restrict__ jets, const float* __restrict__ dads, const float* __restrict__ W_emb,
  const float* __restrict__ W_msg, const float* __restrict__ Wz, const float* __restrict__ Uz,
  const float* __restrict__ Wr, const float* __restrict__ Ur, const float* __restrict__ Wh,
  const float* __restrict__ Uh, const float* __restrict__ W_r1,
  u16* __restrict__ jp, u16* __restrict__ dadsb, u16* __restrict__ Wet, u16* __restrict__ Wmt,
  u16* __restrict__ Wzt, u16* __restrict__ Uzt, u16* __restrict__ Wrt, u16* __restrict__ Urt,
  u16* __restrict__ Wht, u16* __restrict__ Uht, u16* __restrict__ Wr1t)
{
  int blk = blockIdx.x, tid = threadIdx.x;
  if(blk < 1280){
    int mi = blk >> 8, k = blk & 255, j = tid;
    const float* src; u16* dst;
    switch(mi){
      case 0: src = W_msg; dst = Wmt;  break;
      case 1: src = Uz;    dst = Uzt;  break;
      case 2: src = Ur;    dst = Urt;  break;
      case 3: src = Uh;    dst = Uht;  break;
      default: src = W_r1; dst = Wr1t; break;
    }
    dst[j*256 + k] = f2bf(src[k*256 + j]);
  } else if(blk < 2144){
    int q = blk - 1280; int mi = q / 288; int k = q - mi*288; int j = tid;
    const float* src; u16* dst;
    switch(mi){ case 0: src = Wz; dst = Wzt; break; case 1: src = Wr; dst = Wrt; break; default: src = Wh; dst = Wht; break; }
    dst[j*WST + k] = (k < 272) ? f2bf(src[k*256 + j]) : (u16)0;
  } else if(blk < 2176){
    int idx = (blk - 2144)*256 + tid;
    int j = idx >> 5, k = idx & 31;
    Wet[idx] = (k < 16) ? f2bf(W_emb[k*256 + j]) : (u16)0;
  } else if(blk < 4224){
    int idx = (blk - 2176)*256 + tid;
    int n = idx >> 5, k = idx & 31;
    jp[idx] = (k < 16) ? f2bf(jets[n*16 + k]) : (u16)0;
  } else {
    int idx = (blk - 4224)*256 + tid;
    f32x4 v = *(const f32x4*)(dads + (size_t)idx*4);
    st4bf(dadsb + (size_t)idx*4, v[0], v[1], v[2], v[3]);
  }
}

// ---------------------------------------------------------------------------
// k_embed2 (R9, +R10 chunk rotation in Phase M): 256 blocks x 64 nodes.
// ---------------------------------------------------------------------------
__global__ void k_embed2(
  u16* __restrict__ h, u16* __restrict__ hmo,
  const u16* __restrict__ jp, const u16* __restrict__ Wet, const float* __restrict__ be,
  const u16* __restrict__ Wmt, const float* __restrict__ bm)
{
  __shared__ u16 smM[64*AST];
  const int tid = threadIdx.x;
  const int wv = tid >> 6, lane = tid & 63, ln = lane & 15, qd = lane >> 4;
  const int blk   = blockIdx.x;
  const int batch = (blk & 7) * 8 + (blk >> 5);
  const int group = (blk >> 3) & 3;
  const int n0 = batch * 256 + group * 64;
  const int b  = batch;
  const int nb = group * 64;
  const int j0w = wv * 64;
  const int c0 = (blk >> 3) & 7;    // R10: de-correlate same-XCD weight reads

  s16x8 jB[4];
#pragma unroll
  for(int i = 0; i < 4; i++) jB[i] = ld8(jp + (size_t)(n0 + i*16 + ln)*32 + qd*8);

  // ---- Phase E: embed ----
#pragma unroll
  for(int t = 0; t < 4; t++){
    s16x8 a = ld8(Wet + (size_t)(j0w + t*16 + ln)*32 + qd*8);
    f32x4 bv = *(const f32x4*)(be + j0w + t*16 + qd*4);
#pragma unroll
    for(int i = 0; i < 4; i++){
      f32x4 acc = {0.f,0.f,0.f,0.f};
      acc = MFMA(a, jB[i], acc);
      f32x4 hv;
#pragma unroll
      for(int r = 0; r < 4; r++) hv[r] = ftanh(acc[r] + bv[r]);
      st4bf(h + (size_t)(n0 + i*16 + ln)*256 + j0w + t*16 + qd*4, hv[0], hv[1], hv[2], hv[3]);
      st4bf(&smM[(i*16 + ln)*AST + j0w + t*16 + qd*4], hv[0], hv[1], hv[2], hv[3]);
    }
  }
  __syncthreads();

  // ---- Phase M: hm = h @ W_msg + b_msg -> [b][j][node] ----
  {
    f32x4 acc[4][4];
#pragma unroll
    for(int t = 0; t < 4; t++)
#pragma unroll
      for(int i = 0; i < 4; i++) acc[t][i] = (f32x4){0.f,0.f,0.f,0.f};
#pragma unroll
    for(int c = 0; c < 8; c++){
      const int cc = (c + c0) & 7;
      s16x8 A[4];
#pragma unroll
      for(int t = 0; t < 4; t++) A[t] = ld8(Wmt + (size_t)(j0w + t*16 + ln)*256 + cc*32 + qd*8);
      s16x8 Bf[4];
#pragma unroll
      for(int i = 0; i < 4; i++) Bf[i] = ldb64p(&smM[(i*16 + ln)*AST + cc*32 + qd*8]);
#pragma unroll
      for(int t = 0; t < 4; t++)
#pragma unroll
        for(int i = 0; i < 4; i++) acc[t][i] = MFMA(A[t], Bf[i], acc[t][i]);
    }
#pragma unroll
    for(int t = 0; t < 4; t++){
      f32x4 bmv = *(const f32x4*)(bm + j0w + t*16 + qd*4);
#pragma unroll
      for(int i = 0; i < 4; i++){
#pragma unroll
        for(int r = 0; r < 4; r++){
          hmo[(size_t)(b*256 + j0w + t*16 + qd*4 + r)*256 + nb + i*16 + ln] =
            f2bf(acc[t][i][r] + bmv[r]);
        }
      }
    }
  }
}

// ---------------------------------------------------------------------------
// k_gru v22 = v15 + R10 chunk rotation (session best: 523.7us total).
// R11/R12 falsified NT cache segregation (doubled HBM writes). The ~46us/
// launch operating point resisted: deeper pipelines (R8, bit-identical),
// more waves (R1, -20%), more blocks (R4, -65%), register rings (R3, -11%),
// persistence (R7, -33x). Per-CU streaming rate ~28 GB/s is the floor for
// this structure; do not touch without a theory that explains R8's null.
// ---------------------------------------------------------------------------
__global__ __launch_bounds__(256,1) void k_gru(
  u16* __restrict__ h,
  const u16* __restrict__ hmi, u16* __restrict__ hmo,
  const u16* __restrict__ dadsb, const u16* __restrict__ jp,
  const u16* __restrict__ Wzt, const u16* __restrict__ Wrt, const u16* __restrict__ Wht,
  const u16* __restrict__ Uzt, const u16* __restrict__ Urt, const u16* __restrict__ Uht,
  const u16* __restrict__ Wmt,
  const float* __restrict__ bz, const float* __restrict__ br, const float* __restrict__ bhb,
  const float* __restrict__ bm)
{
  __shared__ u16 smM[64*AST];                       // m, later h_new
  __shared__ u16 smB[64*AST];                       // rh
  __shared__ __align__(16) u16 stg[4][2][2][2048];  // [wave][buf][mat] 64 KB
  const int tid = threadIdx.x;
  const int wv = tid >> 6, lane = tid & 63, ln = lane & 15, qd = lane >> 4;
  const int blk   = blockIdx.x;
  const int batch = (blk & 7) * 8 + (blk >> 5);
  const int group = (blk >> 3) & 3;
  const int n0 = batch * 256 + group * 64;
  const int b  = batch;
  const int nb = group * 64;
  const int j0w = wv * 64;                 // wave's 64-wide j-quarter
  const int c0 = (blk >> 3) & 7;           // R10 rotation offset
#define CHK(x) (((x) + c0) & 7)

  u16* s0 = &stg[wv][0][0][0];
  u16* s1 = &stg[wv][1][0][0];
  u16* u0 = &stg[wv][0][1][0];
  u16* u1 = &stg[wv][1][1][0];

  // per-lane DMA source addressing (row = lane>>2, XOR-swizzled col)
  const int rw = lane >> 2;
  const int cs = ((lane & 3) ^ ((lane >> 3) & 3)) * 8;

  // stage1 chunk-0 prefetch ASAP
  const u16* laneA = hmi + (size_t)(b*256 + j0w + rw)*256 + cs;
  dma4(laneA, 256, CHK(0), s0);

  s16x8 jB[4];
#pragma unroll
  for(int i = 0; i < 4; i++) jB[i] = ld8(jp + (size_t)(n0 + i*16 + ln)*32 + qd*8);

  // ================= stage1: m = tanh(dads @ hm) =================
  {
    f32x4 acc[4][4];
#pragma unroll
    for(int t = 0; t < 4; t++)
#pragma unroll
      for(int i = 0; i < 4; i++) acc[t][i] = (f32x4){0.f,0.f,0.f,0.f};
    s16x8 Bf[4], Bn[4];
#pragma unroll
    for(int i = 0; i < 4; i++) Bf[i] = ld8(dadsb + (size_t)(n0 + i*16 + ln)*256 + CHK(0)*32 + qd*8);
#pragma unroll
    for(int c = 0; c < 8; c++){
      u16* cur = (c & 1) ? s1 : s0;
      if(c < 7){
        dma4(laneA, 256, CHK(c+1), (c & 1) ? s0 : s1);
#pragma unroll
        for(int i = 0; i < 4; i++) Bn[i] = ld8(dadsb + (size_t)(n0 + i*16 + ln)*256 + CHK(c+1)*32 + qd*8);
        WAITVM(8);
      } else {
        WAITVM(0);
      }
#pragma unroll
      for(int t = 0; t < 4; t++){
        s16x8 A = AFRAG(cur, t);
#pragma unroll
        for(int i = 0; i < 4; i++) acc[t][i] = MFMA(A, Bf[i], acc[t][i]);
      }
      if(c < 7){
#pragma unroll
        for(int i = 0; i < 4; i++) Bf[i] = Bn[i];
      }
    }
#pragma unroll
    for(int t = 0; t < 4; t++)
#pragma unroll
      for(int i = 0; i < 4; i++)
        st4bf(&smM[(i*16 + ln)*AST + j0w + t*16 + qd*4],
              ftanh(acc[t][i][0]), ftanh(acc[t][i][1]), ftanh(acc[t][i][2]), ftanh(acc[t][i][3]));
  }
  // r-phase chunk-0 prefetch before the barrier (wave-private buffers)
  const u16* laneWr = Wrt + (size_t)(j0w + rw)*WST + cs;
  const u16* laneUr = Urt + (size_t)(j0w + rw)*256 + cs;
  dma4(laneWr, WST, CHK(0), s0);
  dma4(laneUr, 256, CHK(0), u0);
  __syncthreads();

  // ================= r-pass: rh = sig(m@Wr + jets@Wr' + h@Ur + br)*h =================
  {
    f32x4 acc[4][4];
#pragma unroll
    for(int t = 0; t < 4; t++)
#pragma unroll
      for(int i = 0; i < 4; i++) acc[t][i] = (f32x4){0.f,0.f,0.f,0.f};
    s16x8 Aj[4];
#pragma unroll
    for(int t = 0; t < 4; t++) Aj[t] = ld8(Wrt + (size_t)(j0w + t*16 + ln)*WST + 256 + qd*8);
    s16x8 Bh[4], Bn[4];
#pragma unroll
    for(int i = 0; i < 4; i++) Bh[i] = ld8(h + (size_t)(n0 + i*16 + ln)*256 + CHK(0)*32 + qd*8);
#pragma unroll
    for(int c = 0; c < 8; c++){
      u16* cw = (c & 1) ? s1 : s0;
      u16* cu = (c & 1) ? u1 : u0;
      if(c < 7){
        dma4(laneWr, WST, CHK(c+1), (c & 1) ? s0 : s1);
        dma4(laneUr, 256, CHK(c+1), (c & 1) ? u0 : u1);
#pragma unroll
        for(int i = 0; i < 4; i++) Bn[i] = ld8(h + (size_t)(n0 + i*16 + ln)*256 + CHK(c+1)*32 + qd*8);
        WAITVM(12);
      } else {
        WAITVM(0);
      }
      s16x8 Bm[4];
#pragma unroll
      for(int i = 0; i < 4; i++) Bm[i] = ldb64p(&smM[(i*16 + ln)*AST + CHK(c)*32 + qd*8]);
#pragma unroll
      for(int t = 0; t < 4; t++){
        s16x8 Aw = AFRAG(cw, t);
#pragma unroll
        for(int i = 0; i < 4; i++) acc[t][i] = MFMA(Aw, Bm[i], acc[t][i]);
      }
#pragma unroll
      for(int t = 0; t < 4; t++){
        s16x8 Au = AFRAG(cu, t);
#pragma unroll
        for(int i = 0; i < 4; i++) acc[t][i] = MFMA(Au, Bh[i], acc[t][i]);
      }
      if(c < 7){
#pragma unroll
        for(int i = 0; i < 4; i++) Bh[i] = Bn[i];
      }
    }
#pragma unroll
    for(int t = 0; t < 4; t++)
#pragma unroll
      for(int i = 0; i < 4; i++) acc[t][i] = MFMA(Aj[t], jB[i], acc[t][i]);
#pragma unroll
    for(int t = 0; t < 4; t++){
      f32x4 bv = *(const f32x4*)(br + j0w + t*16 + qd*4);
#pragma unroll
      for(int i = 0; i < 4; i++){
        f32x4 hv = ld4bf(h + (size_t)(n0 + i*16 + ln)*256 + j0w + t*16 + qd*4);
        st4bf(&smB[(i*16 + ln)*AST + j0w + t*16 + qd*4],
              fsigm(acc[t][i][0]+bv[0])*hv[0], fsigm(acc[t][i][1]+bv[1])*hv[1],
              fsigm(acc[t][i][2]+bv[2])*hv[2], fsigm(acc[t][i][3]+bv[3])*hv[3]);
      }
    }
  }
  // z-phase chunk-0 prefetch (after epilogue so its hv-load waits don't drain us)
  const u16* laneWz = Wzt + (size_t)(j0w + rw)*WST + cs;
  const u16* laneUz = Uzt + (size_t)(j0w + rw)*256 + cs;
  dma4(laneWz, WST, CHK(0), s0);
  dma4(laneUz, 256, CHK(0), u0);
  __syncthreads();

  // ================= z-phase: zacc = m@Wz + jets@Wz' + h@Uz =================
  f32x4 zacc[4][4], gacc[4][4];
#pragma unroll
  for(int t = 0; t < 4; t++)
#pragma unroll
    for(int i = 0; i < 4; i++) zacc[t][i] = (f32x4){0.f,0.f,0.f,0.f};
  {
    s16x8 Aj[4];
#pragma unroll
    for(int t = 0; t < 4; t++) Aj[t] = ld8(Wzt + (size_t)(j0w + t*16 + ln)*WST + 256 + qd*8);
    s16x8 Bh[4], Bn[4];
#pragma unroll
    for(int i = 0; i < 4; i++) Bh[i] = ld8(h + (size_t)(n0 + i*16 + ln)*256 + CHK(0)*32 + qd*8);
#pragma unroll
    for(int c = 0; c < 8; c++){
      u16* cw = (c & 1) ? s1 : s0;
      u16* cu = (c & 1) ? u1 : u0;
      if(c < 7){
        dma4(laneWz, WST, CHK(c+1), (c & 1) ? s0 : s1);
        dma4(laneUz, 256, CHK(c+1), (c & 1) ? u0 : u1);
#pragma unroll
        for(int i = 0; i < 4; i++) Bn[i] = ld8(h + (size_t)(n0 + i*16 + ln)*256 + CHK(c+1)*32 + qd*8);
        WAITVM(12);
      } else {
        WAITVM(0);
      }
      s16x8 Bm[4];
#pragma unroll
      for(int i = 0; i < 4; i++) Bm[i] = ldb64p(&smM[(i*16 + ln)*AST + CHK(c)*32 + qd*8]);
#pragma unroll
      for(int t = 0; t < 4; t++){
        s16x8 Aw = AFRAG(cw, t);
#pragma unroll
        for(int i = 0; i < 4; i++) zacc[t][i] = MFMA(Aw, Bm[i], zacc[t][i]);
      }
#pragma unroll
      for(int t = 0; t < 4; t++){
        s16x8 Au = AFRAG(cu, t);
#pragma unroll
        for(int i = 0; i < 4; i++) zacc[t][i] = MFMA(Au, Bh[i], zacc[t][i]);
      }
      if(c < 7){
#pragma unroll
        for(int i = 0; i < 4; i++) Bh[i] = Bn[i];
      }
    }
#pragma unroll
    for(int t = 0; t < 4; t++)
#pragma unroll
      for(int i = 0; i < 4; i++) zacc[t][i] = MFMA(Aj[t], jB[i], zacc[t][i]);
  }

  // g-phase chunk-0 prefetch (no barrier needed; z's last chunk read buf1)
  const u16* laneWh = Wht + (size_t)(j0w + rw)*WST + cs;
  const u16* laneUh = Uht + (size_t)(j0w + rw)*256 + cs;
  dma4(laneWh, WST, CHK(0), s0);
  dma4(laneUh, 256, CHK(0), u0);

  // ================= g-phase: gacc = m@Wh + jets@Wh' + rh@Uh =================
#pragma unroll
  for(int t = 0; t < 4; t++)
#pragma unroll
    for(int i = 0; i < 4; i++) gacc[t][i] = (f32x4){0.f,0.f,0.f,0.f};
  {
    s16x8 Aj[4];
#pragma unroll
    for(int t = 0; t < 4; t++) Aj[t] = ld8(Wht + (size_t)(j0w + t*16 + ln)*WST + 256 + qd*8);
#pragma unroll
    for(int c = 0; c < 8; c++){
      u16* cw = (c & 1) ? s1 : s0;
      u16* cu = (c & 1) ? u1 : u0;
      if(c < 7){
        dma4(laneWh, WST, CHK(c+1), (c & 1) ? s0 : s1);
        dma4(laneUh, 256, CHK(c+1), (c & 1) ? u0 : u1);
        WAITVM(8);
      } else {
        WAITVM(0);
      }
      s16x8 Bm[4], Brh[4];
#pragma unroll
      for(int i = 0; i < 4; i++){
        Bm[i]  = ldb64p(&smM[(i*16 + ln)*AST + CHK(c)*32 + qd*8]);
        Brh[i] = ldb64p(&smB[(i*16 + ln)*AST + CHK(c)*32 + qd*8]);
      }
#pragma unroll
      for(int t = 0; t < 4; t++){
        s16x8 Aw = AFRAG(cw, t);
#pragma unroll
        for(int i = 0; i < 4; i++) gacc[t][i] = MFMA(Aw, Bm[i], gacc[t][i]);
      }
#pragma unroll
      for(int t = 0; t < 4; t++){
        s16x8 Au = AFRAG(cu, t);
#pragma unroll
        for(int i = 0; i < 4; i++) gacc[t][i] = MFMA(Au, Brh[i], gacc[t][i]);
      }
    }
#pragma unroll
    for(int t = 0; t < 4; t++)
#pragma unroll
      for(int i = 0; i < 4; i++) gacc[t][i] = MFMA(Aj[t], jB[i], gacc[t][i]);
  }
  __syncthreads();   // all smM/smB reads complete before epilogue overwrites smM

  // ================= epilogue: h_new = h + z*(tanh(g)-h) =================
#pragma unroll
  for(int t = 0; t < 4; t++){
    f32x4 bzv = *(const f32x4*)(bz + j0w + t*16 + qd*4);
    f32x4 bhv = *(const f32x4*)(bhb + j0w + t*16 + qd*4);
#pragma unroll
    for(int i = 0; i < 4; i++){
      f32x4 hv = ld4bf(h + (size_t)(n0 + i*16 + ln)*256 + j0w + t*16 + qd*4);
      f32x4 hn;
#pragma unroll
      for(int r = 0; r < 4; r++){
        float z  = fsigm(zacc[t][i][r] + bzv[r]);
        float th = ftanh(gacc[t][i][r] + bhv[r]);
        hn[r] = hv[r] + z * (th - hv[r]);
      }
      st4bf(h + (size_t)(n0 + i*16 + ln)*256 + j0w + t*16 + qd*4, hn[0], hn[1], hn[2], hn[3]);
      st4bf(&smM[(i*16 + ln)*AST + j0w + t*16 + qd*4], hn[0], hn[1], hn[2], hn[3]);
    }
  }
  // msg chunk-0 prefetch (after epilogue, before barrier)
  const u16* laneWm = Wmt + (size_t)(j0w + rw)*256 + cs;
  dma4(laneWm, 256, CHK(0), s0);
  __syncthreads();

  // ================= msg: hm_out = h_new @ W_msg + b_msg -> [b][h][node] =================
  {
    f32x4 acc[4][4];
#pragma unroll
    for(int t = 0; t < 4; t++)
#pragma unroll
      for(int i = 0; i < 4; i++) acc[t][i] = (f32x4){0.f,0.f,0.f,0.f};
#pragma unroll
    for(int c = 0; c < 8; c++){
      u16* cur = (c & 1) ? s1 : s0;
      if(c < 7){
        dma4(laneWm, 256, CHK(c+1), (c & 1) ? s0 : s1);
        WAITVM(4);
      } else {
        WAITVM(0);
      }
      s16x8 Bf[4];
#pragma unroll
      for(int i = 0; i < 4; i++) Bf[i] = ldb64p(&smM[(i*16 + ln)*AST + CHK(c)*32 + qd*8]);
#pragma unroll
      for(int t = 0; t < 4; t++){
        s16x8 A = AFRAG(cur, t);
#pragma unroll
        for(int i = 0; i < 4; i++) acc[t][i] = MFMA(A, Bf[i], acc[t][i]);
      }
    }
#pragma unroll
    for(int t = 0; t < 4; t++){
      f32x4 bmv = *(const f32x4*)(bm + j0w + t*16 + qd*4);
#pragma unroll
      for(int i = 0; i < 4; i++){
#pragma unroll
        for(int r = 0; r < 4; r++){
          hmo[(size_t)(b*256 + j0w + t*16 + qd*4 + r)*256 + nb + i*16 + ln] =
            f2bf(acc[t][i][r] + bmv[r]);
        }
      }
    }
  }
#undef CHK
}

// ---------------------------------------------------------------------------
// k_tred (R9, +R10 rotation): fused readout stage-1 + node-sum.
// ---------------------------------------------------------------------------
__global__ void k_tred(
  const u16* __restrict__ h, float* __restrict__ sred,
  const u16* __restrict__ Wr1t, const float* __restrict__ br1)
{
  const int tid = threadIdx.x;
  const int wv = tid >> 6, lane = tid & 63, ln = lane & 15, qd = lane >> 4;
  const int blk   = blockIdx.x;
  const int batch = (blk & 7) * 8 + (blk >> 5);
  const int group = (blk >> 3) & 3;
  const int n0 = batch * 256 + group * 64;
  const int j0w = wv * 64;
  const int c0 = (blk >> 3) & 7;

  f32x4 acc[4][4];
#pragma unroll
  for(int t = 0; t < 4; t++)
#pragma unroll
    for(int i = 0; i < 4; i++) acc[t][i] = (f32x4){0.f,0.f,0.f,0.f};
#pragma unroll
  for(int c = 0; c < 8; c++){
    const int cc = (c + c0) & 7;
    s16x8 A[4];
#pragma unroll
    for(int t = 0; t < 4; t++) A[t] = ld8(Wr1t + (size_t)(j0w + t*16 + ln)*256 + cc*32 + qd*8);
    s16x8 Bf[4];
#pragma unroll
    for(int i = 0; i < 4; i++) Bf[i] = ld8(h + (size_t)(n0 + i*16 + ln)*256 + cc*32 + qd*8);
#pragma unroll
    for(int t = 0; t < 4; t++)
#pragma unroll
      for(int i = 0; i < 4; i++) acc[t][i] = MFMA(A[t], Bf[i], acc[t][i]);
  }
#pragma unroll
  for(int t = 0; t < 4; t++){
    f32x4 bv = *(const f32x4*)(br1 + j0w + t*16 + qd*4);
    f32x4 s = {0.f,0.f,0.f,0.f};
#pragma unroll
    for(int i = 0; i < 4; i++)
#pragma unroll
      for(int r = 0; r < 4; r++) s[r] += ftanh(acc[t][i][r] + bv[r]);
    // cross-lane sum over ln (16 lanes share (qd,t,r) => same j)
#pragma unroll
    for(int r = 0; r < 4; r++){
      float v = s[r];
      v += __shfl_xor(v, 1);
      v += __shfl_xor(v, 2);
      v += __shfl_xor(v, 4);
      v += __shfl_xor(v, 8);
      s[r] = v;
    }
    if(ln == 0){
      *(f32x4*)&sred[(size_t)(batch*4 + group)*256 + j0w + t*16 + qd*4] = s;
    }
  }
}

// ---------------------------------------------------------------------------
// k_red2 (R9, +R10 k-rotation): out = 256*b_r2 + (sum_g sred) @ W_r2.
// ---------------------------------------------------------------------------
__global__ void k_red2(const float* __restrict__ sred, const float* __restrict__ W_r2,
                       const float* __restrict__ b_r2, float* __restrict__ out){
  __shared__ float red[4][64];
  const int blk = blockIdx.x;
  const int b = blk >> 2, jq = blk & 3;
  const int jl = threadIdx.x & 63, kq = threadIdx.x >> 6;
  const int j = jq*64 + jl;
  const float* s0 = sred + (size_t)b*4*256;
  float acc = 0.f;
  for(int kk = 0; kk < 64; kk++){
    int k = kq*64 + ((kk + b) & 63);   // rotate: 64 same-tile blocks de-correlate
    float s = s0[k] + s0[256 + k] + s0[512 + k] + s0[768 + k];
    acc += s * W_r2[(size_t)k*256 + j];
  }
  red[kq][jl] = acc;
  __syncthreads();
  if(kq == 0){
    out[(size_t)b*256 + j] = 256.f * b_r2[j] + red[0][jl] + red[1][jl] + red[2][jl] + red[3][jl];
  }
}

extern "C" void kernel_launch(void* const* d_in, const int* in_sizes, int n_in,
                              void* d_out, int out_size, void* d_ws, size_t ws_size,
                              hipStream_t stream)
{
  const float* jets  = (const float*)d_in[0];
  const float* dads  = (const float*)d_in[1];
  const float* W_emb = (const float*)d_in[2];
  const float* b_emb = (const float*)d_in[3];
  const float* W_msg = (const float*)d_in[4];
  const float* b_msg = (const float*)d_in[5];
  const float* Wz    = (const float*)d_in[6];
  const float* Uz    = (const float*)d_in[7];
  const float* bz    = (const float*)d_in[8];
  const float* Wr    = (const float*)d_in[9];
  const float* Ur    = (const float*)d_in[10];
  const float* br    = (const float*)d_in[11];
  const float* Wh    = (const float*)d_in[12];
  const float* Uh    = (const float*)d_in[13];
  const float* bh    = (const float*)d_in[14];
  const float* W_r1  = (const float*)d_in[15];
  const float* b_r1  = (const float*)d_in[16];
  const float* W_r2  = (const float*)d_in[17];
  const float* b_r2  = (const float*)d_in[18];

  char* ws = (char*)d_ws;
  u16* h      = (u16*)(ws);                    // 8 MB  [16384][256] bf16
  u16* hmA    = (u16*)(ws + 8388608);          // 8 MB  [64][256 h][256 node] bf16
  u16* hmB    = (u16*)(ws + 16777216);         // 8 MB  (free after gru: reused for sred)
  u16* dadsb  = (u16*)(ws + 25165824);         // 8 MB  [16384][256] bf16
  u16* jp     = (u16*)(ws + 33554432);         // 1 MB  [16384][32] bf16
  u16* Wmt    = (u16*)(ws + 34603008);
  u16* Uzt    = (u16*)(ws + 34734080);
  u16* Urt    = (u16*)(ws + 34865152);
  u16* Uht    = (u16*)(ws + 34996224);
  u16* Wr1t   = (u16*)(ws + 35127296);
  u16* Wzt    = (u16*)(ws + 35258368);
  u16* Wrt    = (u16*)(ws + 35405824);
  u16* Wht    = (u16*)(ws + 35553280);
  u16* Wet    = (u16*)(ws + 35700736);
  float* sred = (float*)(ws + 16777216);       // 256 KB f32 [64*4][256] (in hmB)
  float* outp = (float*)d_out;

  k_prep<<<8320, 256, 0, stream>>>(jets, dads, W_emb, W_msg, Wz, Uz, Wr, Ur, Wh, Uh, W_r1,
                                   jp, dadsb, Wet, Wmt, Wzt, Uzt, Wrt, Urt, Wht, Uht, Wr1t);
  k_embed2<<<256, 256, 0, stream>>>(h, hmA, jp, Wet, b_emb, Wmt, b_msg);
  for(int it = 0; it < 10; ++it){
    const u16* hin = (it & 1) ? hmB : hmA;
    u16* hout      = (it & 1) ? hmA : hmB;
    k_gru<<<256, 256, 0, stream>>>(h, hin, hout, dadsb, jp,
                                   Wzt, Wrt, Wht, Uzt, Urt, Uht, Wmt,
                                   bz, br, bh, b_msg);
  }
  // it=9 wrote hmA, so hmB region is free: sred lives there
  k_tred<<<256, 256, 0, stream>>>(h, sred, Wr1t, b_r1);
  k_red2<<<256, 256, 0, stream>>>(sred, W_r2, b_r2, outp);
}